// Round 5
// baseline (422.433 us; speedup 1.0000x reference)
//
#include <hip/hip_runtime.h>

// Problem constants
#define B_     16384
#define TD     512     // T*D
#define HID    128
#define LAT    512     // N_TOKENS*CODE_DIM
#define NCODES 512
#define CDIM   64
#define NTOK   8
#define EPS    1e-5f
#define MARGIN 0.02f   // ~200x worst-case 3-pass scoring error; rescue if gap smaller

typedef unsigned short u16;
typedef unsigned int   u32;
typedef short bf16x8 __attribute__((ext_vector_type(8)));   // 8 bf16 = 4 VGPR (MFMA A/B frag)
typedef float f32x4  __attribute__((ext_vector_type(4)));   // MFMA C/D frag

__device__ __forceinline__ u16 bf16_rn(float f){
    u32 u = __float_as_uint(f);
    return (u16)((u + 0x7fffu + ((u >> 16) & 1u)) >> 16);   // round-nearest-even
}
__device__ __forceinline__ float bf16_f(u16 h){ return __uint_as_float(((u32)h) << 16); }
__device__ __forceinline__ void split2(float f, u16& h1, u16& h2){
    h1 = bf16_rn(f);
    h2 = bf16_rn(f - bf16_f(h1));          // residual ~2^-18 |f|
}
__device__ __forceinline__ void split3(float f, u16& h1, u16& h2, u16& h3){
    h1 = bf16_rn(f);
    float r1 = f - bf16_f(h1);
    h2 = bf16_rn(r1);
    h3 = bf16_rn(r1 - bf16_f(h2));         // residual ~2^-27 |f|
}
#define MFMA16(a,b,c) __builtin_amdgcn_mfma_f32_16x16x32_bf16((a),(b),(c),0,0,0)

// ---------------------------------------------------------------------------
// Preps
// ---------------------------------------------------------------------------
__global__ void c2_kernel(const float* __restrict__ cb, float* __restrict__ c2) {
    int c = blockIdx.x, d = threadIdx.x;
    float v = cb[c * CDIM + d];
    float s = v * v;
#pragma unroll
    for (int m = 32; m >= 1; m >>= 1) s += __shfl_xor(s, m, 64);
    if (d == 0) c2[c] = s;
}

// transpose+split3 W[K][N] -> 3 bf16 planes [N][K]
__global__ void tsplit3_kernel(const float* __restrict__ W, u16* __restrict__ p1,
                               u16* __restrict__ p2, u16* __restrict__ p3,
                               int N, int kshift){
    int id = blockIdx.x * 256 + threadIdx.x;
    int K = 1 << kshift;
    int n = id >> kshift, k = id & (K - 1);
    u16 a, b, c; split3(W[(size_t)k * N + n], a, b, c);
    p1[id] = a; p2[id] = b; p3[id] = c;
}
// transpose+split2 W[K][N] -> 2 bf16 planes [N][K]
__global__ void tsplit_kernel(const float* __restrict__ W, u16* __restrict__ hi,
                              u16* __restrict__ lo, int N, int kshift){
    int id = blockIdx.x * 256 + threadIdx.x;
    int K = 1 << kshift;
    int n = id >> kshift, k = id & (K - 1);
    u16 h, l2; split2(W[(size_t)k * N + n], h, l2);
    hi[id] = h; lo[id] = l2;
}
// split2 codebook [512][64] (no transpose)
__global__ void csplit_kernel(const float* __restrict__ C, u16* __restrict__ hi,
                              u16* __restrict__ lo){
    int id = blockIdx.x * 256 + threadIdx.x;
    u16 h, l2; split2(C[id], h, l2);
    hi[id] = h; lo[id] = l2;
}
// P[c][t][j] = sum_k cb[c][k] * dec_w1[t*64+k][j]  (replaces decoder GEMM1)
__global__ void pprep_kernel(const float* __restrict__ cb, const float* __restrict__ dw1,
                             float* __restrict__ P){
    int c = blockIdx.x, t = blockIdx.y, j = threadIdx.x;
    const float* wp = dw1 + (size_t)t * 64 * HID + j;
    const float* cp = cb + (size_t)c * CDIM;
    float acc = 0.f;
#pragma unroll
    for (int k = 0; k < 64; ++k) acc = fmaf(cp[k], wp[(size_t)k * HID], acc);
    P[((size_t)c * 8 + t) * HID + j] = acc;
}

// ---------------------------------------------------------------------------
// 6-pass (3-way-split) MFMA GEMM: fp32-class accuracy on matrix cores.
// C = A @ W (+bias/LN per mode). BM=128, BN=128, BK=32, 4 waves (2Mx2N).
// AFP32: A fp32, split3 on the fly.  Else: A from pre-split planes A1/A2/A3.
// PARTIAL: write raw fp32 acc to Po (k-slice selected by blockIdx.z; no bias).
// LNZ: bias + LayerNorm per 64-col token group, write fp32 z.
// LDS chunk layout [pl][row*4 + (ch ^ ((row>>1)&3))] (proven gemm_split).
// ---------------------------------------------------------------------------
template<bool AFP32, bool PARTIAL, bool LNZ>
__launch_bounds__(256, 2)
__global__ void gemm6(const float* __restrict__ Af,
                      const u16* __restrict__ A1, const u16* __restrict__ A2, const u16* __restrict__ A3,
                      const u16* __restrict__ B1, const u16* __restrict__ B2, const u16* __restrict__ B3,
                      const float* __restrict__ bias,
                      float* __restrict__ P0, float* __restrict__ P1,
                      float* __restrict__ Zo,
                      int M, int N, int K, int ksteps)
{
    __shared__ uint4 As[3][128 * 4];   // 24KB
    __shared__ uint4 Bs[3][128 * 4];   // 24KB

    const int tid = threadIdx.x;
    const int wid = tid >> 6, l = tid & 63, ln = l & 15, kg = l >> 4;
    const int mw = wid >> 1, nw = wid & 1;
    const int m0 = blockIdx.x * 128, n0 = blockIdx.y * 128;
    const int kbase = blockIdx.z * ksteps * 32;
    const int swz = (ln >> 1) & 3;

    f32x4 acc[4][4];
#pragma unroll
    for (int i = 0; i < 4; ++i)
#pragma unroll
        for (int j = 0; j < 4; ++j) acc[i][j] = (f32x4){0.f, 0.f, 0.f, 0.f};

    float4 rx[4];        // AFP32 staging
    uint4  ra[6];        // plane-A staging
    uint4  rb[6];        // B staging

    const int axr = tid >> 1, axc0 = (tid & 1) * 16;   // AFP32: row, col base

    auto gload = [&](int k0){
        if constexpr (AFP32){
            const float* p = Af + (size_t)(m0 + axr) * K + k0 + axc0;
#pragma unroll
            for (int q = 0; q < 4; ++q) rx[q] = *(const float4*)(p + q * 4);
        } else {
#pragma unroll
            for (int h = 0; h < 6; ++h){
                int idx = tid + 256 * h;                 // 0..1535
                int pl = idx >> 9, rem = idx & 511, r = rem >> 2, c = rem & 3;
                const u16* src = (pl == 0 ? A1 : pl == 1 ? A2 : A3);
                ra[h] = *(const uint4*)(src + (size_t)(m0 + r) * K + k0 + c * 8);
            }
        }
#pragma unroll
        for (int h = 0; h < 6; ++h){
            int idx = tid + 256 * h;
            int pl = idx >> 9, rem = idx & 511, r = rem >> 2, c = rem & 3;
            const u16* src = (pl == 0 ? B1 : pl == 1 ? B2 : B3);
            rb[h] = *(const uint4*)(src + (size_t)(n0 + r) * K + k0 + c * 8);
        }
    };
    auto lstore = [&](){
        if constexpr (AFP32){
            float v[16];
#pragma unroll
            for (int q = 0; q < 4; ++q){ v[q*4]=rx[q].x; v[q*4+1]=rx[q].y; v[q*4+2]=rx[q].z; v[q*4+3]=rx[q].w; }
#pragma unroll
            for (int half = 0; half < 2; ++half){
                u16 s1[8] __attribute__((aligned(16)));
                u16 s2[8] __attribute__((aligned(16)));
                u16 s3[8] __attribute__((aligned(16)));
#pragma unroll
                for (int j = 0; j < 8; ++j) split3(v[half * 8 + j], s1[j], s2[j], s3[j]);
                int ch = axc0 / 8 + half;
                int pc = axr * 4 + (ch ^ ((axr >> 1) & 3));
                As[0][pc] = *(const uint4*)s1;
                As[1][pc] = *(const uint4*)s2;
                As[2][pc] = *(const uint4*)s3;
            }
        } else {
#pragma unroll
            for (int h = 0; h < 6; ++h){
                int idx = tid + 256 * h;
                int pl = idx >> 9, rem = idx & 511, r = rem >> 2, c = rem & 3;
                As[pl][r * 4 + (c ^ ((r >> 1) & 3))] = ra[h];
            }
        }
#pragma unroll
        for (int h = 0; h < 6; ++h){
            int idx = tid + 256 * h;
            int pl = idx >> 9, rem = idx & 511, r = rem >> 2, c = rem & 3;
            Bs[pl][r * 4 + (c ^ ((r >> 1) & 3))] = rb[h];
        }
    };

    gload(kbase);
    for (int s = 0; s < ksteps; ++s){
        if (s) __syncthreads();
        lstore();
        __syncthreads();
        if (s + 1 < ksteps) gload(kbase + (s + 1) * 32);

        bf16x8 af[4][3], bq[4][3];
#pragma unroll
        for (int mi = 0; mi < 4; ++mi){
            int r = mw * 64 + mi * 16 + ln;
#pragma unroll
            for (int pl = 0; pl < 3; ++pl) af[mi][pl] = *(bf16x8*)&As[pl][r * 4 + (kg ^ swz)];
        }
#pragma unroll
        for (int ni = 0; ni < 4; ++ni){
            int r = nw * 64 + ni * 16 + ln;
#pragma unroll
            for (int pl = 0; pl < 3; ++pl) bq[ni][pl] = *(bf16x8*)&Bs[pl][r * 4 + (kg ^ swz)];
        }
#pragma unroll
        for (int mi = 0; mi < 4; ++mi)
#pragma unroll
            for (int ni = 0; ni < 4; ++ni){
                acc[mi][ni] = MFMA16(af[mi][0], bq[ni][0], acc[mi][ni]);  // a1b1
                acc[mi][ni] = MFMA16(af[mi][0], bq[ni][1], acc[mi][ni]);  // a1b2
                acc[mi][ni] = MFMA16(af[mi][1], bq[ni][0], acc[mi][ni]);  // a2b1
                acc[mi][ni] = MFMA16(af[mi][1], bq[ni][1], acc[mi][ni]);  // a2b2
                acc[mi][ni] = MFMA16(af[mi][0], bq[ni][2], acc[mi][ni]);  // a1b3
                acc[mi][ni] = MFMA16(af[mi][2], bq[ni][0], acc[mi][ni]);  // a3b1
            }
    }

    // Epilogue. C/D frag: col = lane&15, row = (lane>>4)*4 + reg  [proven]
    if constexpr (PARTIAL){
        float* Po = blockIdx.z ? P1 : P0;
#pragma unroll
        for (int mi = 0; mi < 4; ++mi)
#pragma unroll
            for (int r = 0; r < 4; ++r){
                size_t row = (size_t)(m0 + mw * 64 + mi * 16 + kg * 4 + r);
#pragma unroll
                for (int ni = 0; ni < 4; ++ni)
                    Po[row * N + nw * 64 + ni * 16 + ln] = acc[mi][ni][r];
            }
    }
    if constexpr (LNZ){
        float bv[4];
#pragma unroll
        for (int ni = 0; ni < 4; ++ni) bv[ni] = bias[n0 + nw * 64 + ni * 16 + ln];
#pragma unroll
        for (int mi = 0; mi < 4; ++mi)
#pragma unroll
            for (int r = 0; r < 4; ++r){
                float v[4];
#pragma unroll
                for (int ni = 0; ni < 4; ++ni) v[ni] = acc[mi][ni][r] + bv[ni];
                float s  = v[0] + v[1] + v[2] + v[3];
                float ss = v[0]*v[0] + v[1]*v[1] + v[2]*v[2] + v[3]*v[3];
#pragma unroll
                for (int mk = 1; mk <= 8; mk <<= 1){
                    s  += __shfl_xor(s,  mk, 64);
                    ss += __shfl_xor(ss, mk, 64);
                }
                float mean = s * (1.f / 64.f);
                float var  = ss * (1.f / 64.f) - mean * mean;
                float rs   = rsqrtf(var + EPS);
                size_t row = (size_t)(m0 + mw * 64 + mi * 16 + kg * 4 + r);
#pragma unroll
                for (int ni = 0; ni < 4; ++ni)
                    Zo[row * 512 + n0 + nw * 64 + ni * 16 + ln] = (v[ni] - mean) * rs;
            }
    }
}

// ---------------------------------------------------------------------------
// enc1b: h = relu(p0 + p1 + b1), write 3-way bf16 planes for enc2
// ---------------------------------------------------------------------------
__global__ void combine_relu_split3(const float* __restrict__ p0, const float* __restrict__ p1,
                                    const float* __restrict__ bias,
                                    u16* __restrict__ H1, u16* __restrict__ H2, u16* __restrict__ H3){
    int id = blockIdx.x * 256 + threadIdx.x;     // over M*128/4 float4 groups
    int c4 = (id & 31) * 4;
    float4 a = *(const float4*)&p0[(size_t)id * 4];
    float4 b = *(const float4*)&p1[(size_t)id * 4];
    float4 bi = *(const float4*)&bias[c4];
    float v[4] = {fmaxf(a.x + b.x + bi.x, 0.f), fmaxf(a.y + b.y + bi.y, 0.f),
                  fmaxf(a.z + b.z + bi.z, 0.f), fmaxf(a.w + b.w + bi.w, 0.f)};
    u16 s1[4] __attribute__((aligned(8)));
    u16 s2[4] __attribute__((aligned(8)));
    u16 s3[4] __attribute__((aligned(8)));
#pragma unroll
    for (int j = 0; j < 4; ++j) split3(v[j], s1[j], s2[j], s3[j]);
    *(uint2*)&H1[(size_t)id * 4] = *(const uint2*)s1;
    *(uint2*)&H2[(size_t)id * 4] = *(const uint2*)s2;
    *(uint2*)&H3[(size_t)id * 4] = *(const uint2*)s3;
}

// ---------------------------------------------------------------------------
// VQ GEMM: tile 128 tokens x 128 codes, K=64 one shot, ONE barrier pair.
// A: z fp32 split2 on the fly into LDS planes. B: codebook planes.
// 3-pass scoring (err ~1e-4 << MARGIN). Per-token (best,2nd,idx) partials.
// LDS rows = 8 chunks, swizzle ch ^ (row&7) (R4-proven, ~0 conflicts).
// ---------------------------------------------------------------------------
__launch_bounds__(256, 2)
__global__ void vq_gemm(const float* __restrict__ zln,
                        const u16* __restrict__ Chi, const u16* __restrict__ Clo,
                        const float* __restrict__ c2,
                        float4* __restrict__ part)     // [token][4 nb] {b1,b2,idx,0}
{
    __shared__ uint4 Az[2][128 * 8];   // 32KB
    __shared__ uint4 Bz[2][128 * 8];   // 32KB
    __shared__ float sB1[2][2][64], sB2[2][2][64];
    __shared__ int   sI[2][2][64];

    const int tid = threadIdx.x;
    const int wid = tid >> 6, l = tid & 63, ln = l & 15, kg = l >> 4;
    const int mw = wid >> 1, nw = wid & 1;
    const int tok0 = blockIdx.x * 128, c0 = blockIdx.y * 128;

    // stage A: 1024 groups of 8 fp32 -> split2 -> 2 planes
#pragma unroll
    for (int h = 0; h < 4; ++h){
        int g = tid + 256 * h;           // 0..1023
        int r = g >> 3, ch = g & 7;
        const float* zp = zln + (size_t)(tok0 + r) * CDIM + ch * 8;
        float4 v0 = *(const float4*)zp, v1 = *(const float4*)(zp + 4);
        float vv[8] = {v0.x, v0.y, v0.z, v0.w, v1.x, v1.y, v1.z, v1.w};
        u16 hs[8] __attribute__((aligned(16)));
        u16 ls[8] __attribute__((aligned(16)));
#pragma unroll
        for (int j = 0; j < 8; ++j) split2(vv[j], hs[j], ls[j]);
        Az[0][r * 8 + (ch ^ (r & 7))] = *(const uint4*)hs;
        Az[1][r * 8 + (ch ^ (r & 7))] = *(const uint4*)ls;
    }
    // stage B: 2048 chunks from pre-split codebook planes
#pragma unroll
    for (int h = 0; h < 8; ++h){
        int idx = tid + 256 * h;
        int pl = idx >> 10, rem = idx & 1023, r = rem >> 3, ch = rem & 7;
        Bz[pl][r * 8 + (ch ^ (r & 7))] =
            *(const uint4*)((pl ? Clo : Chi) + (size_t)(c0 + r) * CDIM + ch * 8);
    }
    __syncthreads();

    bf16x8 am[4][2][2], bm[4][2][2];   // [frag][ks][plane]
#pragma unroll
    for (int mi = 0; mi < 4; ++mi){
        int r = mw * 64 + mi * 16 + ln;
#pragma unroll
        for (int ks = 0; ks < 2; ++ks){
            int c = ks * 4 + kg;
            am[mi][ks][0] = *(bf16x8*)&Az[0][r * 8 + (c ^ (r & 7))];
            am[mi][ks][1] = *(bf16x8*)&Az[1][r * 8 + (c ^ (r & 7))];
        }
    }
#pragma unroll
    for (int ni = 0; ni < 4; ++ni){
        int r = nw * 64 + ni * 16 + ln;
#pragma unroll
        for (int ks = 0; ks < 2; ++ks){
            int c = ks * 4 + kg;
            bm[ni][ks][0] = *(bf16x8*)&Bz[0][r * 8 + (c ^ (r & 7))];
            bm[ni][ks][1] = *(bf16x8*)&Bz[1][r * 8 + (c ^ (r & 7))];
        }
    }

    f32x4 acc[4][4];
#pragma unroll
    for (int i = 0; i < 4; ++i)
#pragma unroll
        for (int j = 0; j < 4; ++j) acc[i][j] = (f32x4){0.f, 0.f, 0.f, 0.f};
#pragma unroll
    for (int mi = 0; mi < 4; ++mi)
#pragma unroll
        for (int ni = 0; ni < 4; ++ni)
#pragma unroll
            for (int ks = 0; ks < 2; ++ks){
                acc[mi][ni] = MFMA16(am[mi][ks][0], bm[ni][ks][0], acc[mi][ni]);  // hh
                acc[mi][ni] = MFMA16(am[mi][ks][0], bm[ni][ks][1], acc[mi][ni]);  // hl
                acc[mi][ni] = MFMA16(am[mi][ks][1], bm[ni][ks][0], acc[mi][ni]);  // lh
            }

    float c2v[4];
#pragma unroll
    for (int ni = 0; ni < 4; ++ni) c2v[ni] = c2[c0 + nw * 64 + ni * 16 + ln];

    // per-token triple: in-lane scan over ni (ascending codes), then butterfly
#pragma unroll
    for (int mi = 0; mi < 4; ++mi)
#pragma unroll
        for (int r4 = 0; r4 < 4; ++r4){
            float v1 = 3.4e38f, v2 = 3.4e38f; int ii = 0;
#pragma unroll
            for (int ni = 0; ni < 4; ++ni){
                float d = fmaf(-2.f, acc[mi][ni][r4], c2v[ni]);
                int code = c0 + nw * 64 + ni * 16 + ln;
                if (d < v1){ v2 = v1; v1 = d; ii = code; }
                else if (d < v2) v2 = d;
            }
#pragma unroll
            for (int mk = 1; mk <= 8; mk <<= 1){
                float o1 = __shfl_xor(v1, mk, 64), o2 = __shfl_xor(v2, mk, 64);
                int   oi = __shfl_xor(ii, mk, 64);
                float n2 = fminf(fmaxf(v1, o1), fminf(v2, o2));
                if (o1 < v1 || (o1 == v1 && oi < ii)){ v1 = o1; ii = oi; }
                v2 = n2;
            }
            if (ln == 0){
                int tl = mi * 16 + kg * 4 + r4;
                sB1[mw][nw][tl] = v1; sB2[mw][nw][tl] = v2; sI[mw][nw][tl] = ii;
            }
        }
    __syncthreads();

    if (tid < 128){
        int mw2 = tid >> 6, tl = tid & 63;
        float v1 = sB1[mw2][0][tl], v2 = sB2[mw2][0][tl]; int ii = sI[mw2][0][tl];
        float o1 = sB1[mw2][1][tl], o2 = sB2[mw2][1][tl]; int oi = sI[mw2][1][tl];
        float n2 = fminf(fmaxf(v1, o1), fminf(v2, o2));
        if (o1 < v1 || (o1 == v1 && oi < ii)){ v1 = o1; ii = oi; }
        v2 = n2;
        part[(size_t)(tok0 + tid) * 4 + blockIdx.y] = make_float4(v1, v2, (float)ii, 0.f);
    }
}

// ---------------------------------------------------------------------------
// VQ finalize: combine 4 partials/token, margin rescue (exact fp32),
// zq/idx outputs, fused dec-GEMM1 via P-table. 64 tokens per 256-thr block.
// ---------------------------------------------------------------------------
__launch_bounds__(256, 4)
__global__ void vq_final(const float4* __restrict__ part, const float* __restrict__ zln,
                         const float* __restrict__ cbf, const float* __restrict__ c2,
                         const float* __restrict__ Ptab, const float* __restrict__ db1,
                         float* __restrict__ zq_o, float* __restrict__ idx_o,
                         u16* __restrict__ h_h, u16* __restrict__ h_l)
{
    __shared__ int   fI[64];
    __shared__ float zf[64];
    __shared__ int   nflag, flagR[64];
    __shared__ float wB[4];
    __shared__ int   wI[4];

    const int tid = threadIdx.x;
    const int wid = tid >> 6, l = tid & 63;
    const int m0 = blockIdx.x * 64;

    if (tid == 0) nflag = 0;
    __syncthreads();

    if (tid < 64){
        const float4* pp = part + (size_t)(m0 + tid) * 4;
        float4 p = pp[0];
        float v1 = p.x, v2 = p.y; int ii = (int)p.z;
#pragma unroll
        for (int nb = 1; nb < 4; ++nb){
            float4 q = pp[nb];
            float o1 = q.x, o2 = q.y; int oi = (int)q.z;
            float n2 = fminf(fmaxf(v1, o1), fminf(v2, o2));
            if (o1 < v1 || (o1 == v1 && oi < ii)){ v1 = o1; ii = oi; }
            v2 = n2;
        }
        fI[tid] = ii;
        if (v2 - v1 < MARGIN){ int s = atomicAdd(&nflag, 1); flagR[s] = tid; }
    }
    __syncthreads();

    // exact fp32 rescue (rare)
    int nf = nflag;
    for (int f = 0; f < nf; ++f){
        int row = flagR[f];
        if (tid < 64) zf[tid] = zln[(size_t)(m0 + row) * CDIM + tid];
        __syncthreads();
        float best = 3.4e38f; int bi = 0;
#pragma unroll
        for (int cH = 0; cH < 2; ++cH){
            int c = tid + 256 * cH;                 // ascending per thread
            const float* cp = cbf + (size_t)c * CDIM;
            float dot = 0.f;
#pragma unroll
            for (int dd = 0; dd < 64; ++dd) dot = fmaf(zf[dd], cp[dd], dot);
            float d = fmaf(-2.f, dot, c2[c]);
            if (d < best){ best = d; bi = c; }
        }
#pragma unroll
        for (int mk = 1; mk < 64; mk <<= 1){
            float o = __shfl_xor(best, mk, 64); int oi = __shfl_xor(bi, mk, 64);
            if (o < best || (o == best && oi < bi)){ best = o; bi = oi; }
        }
        if (l == 0){ wB[wid] = best; wI[wid] = bi; }
        __syncthreads();
        if (tid == 0){
            float v1 = wB[0]; int ii = wI[0];
#pragma unroll
            for (int w2 = 1; w2 < 4; ++w2)
                if (wB[w2] < v1 || (wB[w2] == v1 && wI[w2] < ii)){ v1 = wB[w2]; ii = wI[w2]; }
            fI[row] = ii;
        }
        __syncthreads();
    }

    // zq (exact fp32 gather) + idx
    {
        int row = tid >> 2, pq = tid & 3;
        int ii  = fI[row];
        size_t gr = (size_t)(m0 + row);
        const float* cf = cbf + (size_t)ii * CDIM + pq * 16;
        float4 q0 = *(const float4*)(cf + 0),  q1 = *(const float4*)(cf + 4);
        float4 q2 = *(const float4*)(cf + 8),  q3 = *(const float4*)(cf + 12);
        float* zo = zq_o + gr * CDIM + pq * 16;
        *(float4*)(zo + 0) = q0; *(float4*)(zo + 4)  = q1;
        *(float4*)(zo + 8) = q2; *(float4*)(zo + 12) = q3;
        if (pq == 0) idx_o[gr] = (float)ii;
    }

    // fused decoder GEMM1: h = relu(b1 + sum_t P[idx_t][t][:]), split2 planes
    {
        int s  = tid >> 5;                 // sample-in-block 0..7
        int j0 = (tid & 31) * 4;
        float4 hv = *(const float4*)&db1[j0];
#pragma unroll
        for (int t = 0; t < 8; ++t){
            int c = fI[s * 8 + t];
            const float* pp = Ptab + ((size_t)c * 8 + t) * HID + j0;
            float4 p = *(const float4*)pp;
            hv.x += p.x; hv.y += p.y; hv.z += p.z; hv.w += p.w;
        }
        float v[4] = {fmaxf(hv.x,0.f), fmaxf(hv.y,0.f), fmaxf(hv.z,0.f), fmaxf(hv.w,0.f)};
        u16 hh[4] __attribute__((aligned(8)));
        u16 ll[4] __attribute__((aligned(8)));
#pragma unroll
        for (int q = 0; q < 4; ++q) split2(v[q], hh[q], ll[q]);
        size_t hrow = ((size_t)blockIdx.x * 8 + s) * HID + j0;
        *(uint2*)&h_h[hrow] = *(const uint2*)hh;
        *(uint2*)&h_l[hrow] = *(const uint2*)ll;
    }
}

// ---------------------------------------------------------------------------
// DECODER GEMM2: split-bf16 MFMA GEMM (3-pass), pre-split planes [proven]
// ---------------------------------------------------------------------------
__launch_bounds__(256, 2)
__global__ void gemm_split(const u16* __restrict__ Ahi, const u16* __restrict__ Alo,
                           const u16* __restrict__ Bhi, const u16* __restrict__ Blo,
                           const float* __restrict__ bias,
                           float* __restrict__ Of,
                           int M, int N, int K)
{
    constexpr int BM = 128;
    __shared__ uint4 As[2][BM * 4];
    __shared__ uint4 Bs[2][128 * 4];

    const int tid = threadIdx.x;
    const int wid = tid >> 6, l = tid & 63, ln = l & 15, kg = l >> 4;
    const int mw = wid >> 1, nw = wid & 1;
    const int m0 = blockIdx.x * BM, n0 = blockIdx.y * 128;
    const int swz = (ln >> 1) & 3;

    f32x4 acc[4][4];
#pragma unroll
    for (int i = 0; i < 4; ++i)
#pragma unroll
        for (int j = 0; j < 4; ++j) acc[i][j] = (f32x4){0.f, 0.f, 0.f, 0.f};

    uint4 ra[4], rb[4];
    auto gload = [&](int k0){
#pragma unroll
        for (int h = 0; h < 4; ++h){
            int idx = tid + 256 * h; int r = idx >> 3, pl = (idx >> 2) & 1, c = idx & 3;
            ra[h] = *(const uint4*)((pl ? Alo : Ahi) + (size_t)(m0 + r) * K + k0 + c * 8);
        }
#pragma unroll
        for (int h = 0; h < 4; ++h){
            int idx = tid + 256 * h; int r = idx >> 3, pl = (idx >> 2) & 1, c = idx & 3;
            rb[h] = *(const uint4*)((pl ? Blo : Bhi) + (size_t)(n0 + r) * K + k0 + c * 8);
        }
    };
    auto lstore = [&](){
#pragma unroll
        for (int h = 0; h < 4; ++h){
            int idx = tid + 256 * h; int r = idx >> 3, pl = (idx >> 2) & 1, c = idx & 3;
            As[pl][r * 4 + (c ^ ((r >> 1) & 3))] = ra[h];
        }
#pragma unroll
        for (int h = 0; h < 4; ++h){
            int idx = tid + 256 * h; int r = idx >> 3, pl = (idx >> 2) & 1, c = idx & 3;
            Bs[pl][r * 4 + (c ^ ((r >> 1) & 3))] = rb[h];
        }
    };

    gload(0);
    for (int k0 = 0; k0 < K; k0 += 32){
        if (k0) __syncthreads();
        lstore();
        __syncthreads();
        if (k0 + 32 < K) gload(k0 + 32);

        bf16x8 af[4][2], bfr[4][2];
#pragma unroll
        for (int mi = 0; mi < 4; ++mi){
            int r = mw * 64 + mi * 16 + ln;
            af[mi][0] = *(bf16x8*)&As[0][r * 4 + (kg ^ swz)];
            af[mi][1] = *(bf16x8*)&As[1][r * 4 + (kg ^ swz)];
        }
#pragma unroll
        for (int ni = 0; ni < 4; ++ni){
            int r = nw * 64 + ni * 16 + ln;
            bfr[ni][0] = *(bf16x8*)&Bs[0][r * 4 + (kg ^ swz)];
            bfr[ni][1] = *(bf16x8*)&Bs[1][r * 4 + (kg ^ swz)];
        }
#pragma unroll
        for (int mi = 0; mi < 4; ++mi)
#pragma unroll
            for (int ni = 0; ni < 4; ++ni){
                acc[mi][ni] = MFMA16(af[mi][0], bfr[ni][0], acc[mi][ni]);
                acc[mi][ni] = MFMA16(af[mi][0], bfr[ni][1], acc[mi][ni]);
                acc[mi][ni] = MFMA16(af[mi][1], bfr[ni][0], acc[mi][ni]);
            }
    }

    float bv[4];
#pragma unroll
    for (int ni = 0; ni < 4; ++ni) bv[ni] = bias[n0 + nw * 64 + ni * 16 + ln];
#pragma unroll
    for (int mi = 0; mi < 4; ++mi)
#pragma unroll
        for (int r = 0; r < 4; ++r){
            size_t row = (size_t)(m0 + mw * 64 + mi * 16 + kg * 4 + r);
#pragma unroll
            for (int ni = 0; ni < 4; ++ni)
                Of[row * N + n0 + nw * 64 + ni * 16 + ln] = acc[mi][ni][r] + bv[ni];
        }
}

// ---------------------------------------------------------------------------
extern "C" void kernel_launch(void* const* d_in, const int* in_sizes, int n_in,
                              void* d_out, int out_size, void* d_ws, size_t ws_size,
                              hipStream_t stream) {
    const float* x      = (const float*)d_in[0];
    const float* enc_w1 = (const float*)d_in[1];
    const float* enc_b1 = (const float*)d_in[2];
    const float* enc_w2 = (const float*)d_in[3];
    const float* enc_b2 = (const float*)d_in[4];
    const float* cbk    = (const float*)d_in[5];
    const float* dec_w1 = (const float*)d_in[6];
    const float* dec_b1 = (const float*)d_in[7];
    const float* dec_w2 = (const float*)d_in[8];
    const float* dec_b2 = (const float*)d_in[9];

    float* out     = (float*)d_out;
    float* recon_o = out;
    float* zq_o    = out + (size_t)B_ * TD;
    float* idx_o   = out + 2 * (size_t)B_ * TD;

    // workspace carve-up
    float* zbuf  = (float*)d_ws;                        // [B,512] fp32 z (post-LN), 33.5MB
    float* Ptab  = zbuf + (size_t)B_ * TD;              // 2MB
    float* c2buf = Ptab + (size_t)NCODES * NTOK * HID;  // 512
    float* part0 = c2buf + 512;                         // enc1 partial k0 / vq partials (8MB)
    float* part1 = part0 + (size_t)B_ * HID;            // enc1 partial k1 / dec h planes (8MB)
    float4* vqpart = (float4*)part0;                    // [131072][4] after enc1b
    u16* h_h = (u16*)part1;                             // dec h planes after enc1b
    u16* h_l = h_h + (size_t)B_ * HID;
    u16* w = (u16*)(part1 + (size_t)B_ * HID);
    u16* w1t1 = w; w += 65536;  u16* w1t2 = w; w += 65536;  u16* w1t3 = w; w += 65536;
    u16* w2t1 = w; w += 65536;  u16* w2t2 = w; w += 65536;  u16* w2t3 = w; w += 65536;
    u16* d2t_h = w; w += 65536; u16* d2t_l = w; w += 65536;
    u16* cb_h = w; w += 32768;  u16* cb_l = w; w += 32768;
    u16* h3a = w; w += (size_t)B_ * HID;   // h split3 planes (4MB ea)
    u16* h3b = w; w += (size_t)B_ * HID;
    u16* h3c = w; w += (size_t)B_ * HID;

    // ---- preps ----
    hipLaunchKernelGGL(tsplit3_kernel, dim3(256), dim3(256), 0, stream, enc_w1, w1t1, w1t2, w1t3, HID, 9);
    hipLaunchKernelGGL(tsplit3_kernel, dim3(256), dim3(256), 0, stream, enc_w2, w2t1, w2t2, w2t3, LAT, 7);
    hipLaunchKernelGGL(tsplit_kernel,  dim3(256), dim3(256), 0, stream, dec_w2, d2t_h, d2t_l, TD, 7);
    hipLaunchKernelGGL(csplit_kernel,  dim3(128), dim3(256), 0, stream, cbk, cb_h, cb_l);
    hipLaunchKernelGGL(c2_kernel, dim3(NCODES), dim3(64), 0, stream, cbk, c2buf);
    hipLaunchKernelGGL(pprep_kernel, dim3(NCODES, NTOK), dim3(HID), 0, stream, cbk, dec_w1, Ptab);

    // ---- enc1a: x @ w1, 6-pass MFMA, split-K (2 halves of 256) -> partials ----
    hipLaunchKernelGGL((gemm6<true, true, false>), dim3(B_ / 128, 1, 2), dim3(256), 0, stream,
                       x, (const u16*)nullptr, (const u16*)nullptr, (const u16*)nullptr,
                       w1t1, w1t2, w1t3, (const float*)nullptr,
                       part0, part1, (float*)nullptr, B_, HID, TD, 8);

    // ---- enc1b: h = relu(p0+p1+b1) -> 3-way planes ----
    hipLaunchKernelGGL(combine_relu_split3, dim3(B_ * HID / 1024), dim3(256), 0, stream,
                       part0, part1, enc_b1, h3a, h3b, h3c);

    // ---- enc2: h @ w2 + LN, 6-pass MFMA -> zbuf fp32 ----
    hipLaunchKernelGGL((gemm6<false, false, true>), dim3(B_ / 128, LAT / 128, 1), dim3(256), 0, stream,
                       (const float*)nullptr, h3a, h3b, h3c,
                       w2t1, w2t2, w2t3, enc_b2,
                       (float*)nullptr, (float*)nullptr, zbuf, B_, LAT, HID, 4);

    // ---- VQ GEMM: 128x128 tiles, partial argmin triples ----
    hipLaunchKernelGGL(vq_gemm, dim3(B_ * NTOK / 128, NCODES / 128), dim3(256), 0, stream,
                       zbuf, cb_h, cb_l, c2buf, vqpart);

    // ---- VQ finalize: combine + rescue + zq/idx + h planes ----
    hipLaunchKernelGGL(vq_final, dim3(B_ * NTOK / 64), dim3(256), 0, stream,
                       vqpart, zbuf, cbk, c2buf, Ptab, dec_b1,
                       zq_o, idx_o, h_h, h_l);

    // ---- dec2: h @ dw2 -> recon ----
    hipLaunchKernelGGL(gemm_split, dim3(B_ / 128, TD / 128), dim3(256), 0, stream,
                       h_h, h_l, d2t_h, d2t_l, dec_b2, recon_o, B_, TD, HID);
}

// Round 6
// 398.496 us; speedup vs baseline: 1.0601x; 1.0601x over previous
//
#include <hip/hip_runtime.h>

// Problem constants
#define B_     16384
#define TD     512     // T*D
#define HID    128
#define LAT    512     // N_TOKENS*CODE_DIM
#define NCODES 512
#define CDIM   64
#define NTOK   8
#define EPS    1e-5f
#define MARGIN 0.02f   // ~200x worst-case 3-pass scoring error; rescue if gap smaller

typedef unsigned short u16;
typedef unsigned int   u32;
typedef short bf16x8 __attribute__((ext_vector_type(8)));   // 8 bf16 = 4 VGPR (MFMA A/B frag)
typedef float f32x4  __attribute__((ext_vector_type(4)));   // MFMA C/D frag

__device__ __forceinline__ u16 bf16_rn(float f){
    u32 u = __float_as_uint(f);
    return (u16)((u + 0x7fffu + ((u >> 16) & 1u)) >> 16);   // round-nearest-even
}
__device__ __forceinline__ float bf16_f(u16 h){ return __uint_as_float(((u32)h) << 16); }
__device__ __forceinline__ void split2(float f, u16& h1, u16& h2){
    h1 = bf16_rn(f);
    h2 = bf16_rn(f - bf16_f(h1));          // residual ~2^-18 |f|
}
#define MFMA16(a,b,c) __builtin_amdgcn_mfma_f32_16x16x32_bf16((a),(b),(c),0,0,0)

// ---------------------------------------------------------------------------
// Preps (all proven R2-R5)
// ---------------------------------------------------------------------------
__global__ void c2_kernel(const float* __restrict__ cb, float* __restrict__ c2) {
    int c = blockIdx.x, d = threadIdx.x;
    float v = cb[c * CDIM + d];
    float s = v * v;
#pragma unroll
    for (int m = 32; m >= 1; m >>= 1) s += __shfl_xor(s, m, 64);
    if (d == 0) c2[c] = s;
}

__global__ void tsplit_kernel(const float* __restrict__ W, u16* __restrict__ hi,
                              u16* __restrict__ lo, int N, int kshift){
    int id = blockIdx.x * 256 + threadIdx.x;
    int K = 1 << kshift;
    int n = id >> kshift, k = id & (K - 1);
    u16 h, l2; split2(W[(size_t)k * N + n], h, l2);
    hi[id] = h; lo[id] = l2;
}

__global__ void csplit_kernel(const float* __restrict__ C, u16* __restrict__ hi,
                              u16* __restrict__ lo){
    int id = blockIdx.x * 256 + threadIdx.x;
    u16 h, l2; split2(C[id], h, l2);
    hi[id] = h; lo[id] = l2;
}

// P[c][t][j] = sum_k cb[c][k] * dec_w1[t*64+k][j]  (replaces decoder GEMM1)
__global__ void pprep_kernel(const float* __restrict__ cb, const float* __restrict__ dw1,
                             float* __restrict__ P){
    int c = blockIdx.x, t = blockIdx.y, j = threadIdx.x;
    const float* wp = dw1 + (size_t)t * 64 * HID + j;
    const float* cp = cb + (size_t)c * CDIM;
    float acc = 0.f;
#pragma unroll
    for (int k = 0; k < 64; ++k) acc = fmaf(cp[k], wp[(size_t)k * HID], acc);
    P[((size_t)c * 8 + t) * HID + j] = acc;
}

// ---------------------------------------------------------------------------
// ENCODER (fp32 reference numerics class): baseline VALU fp32 tiled GEMM.
// ZP epilogue also writes z as bf16 hi/lo planes [token][64] (z unchanged).
// [proven R2-R4 — do not touch]
// ---------------------------------------------------------------------------
template<bool RELU, bool LN, bool ZP>
__launch_bounds__(256)
__global__ void gemm_kernel(const float* __restrict__ A, const float* __restrict__ W,
                            const float* __restrict__ bias,
                            float* __restrict__ C,
                            u16* __restrict__ zph, u16* __restrict__ zpl,
                            int M, int N, int K) {
    constexpr int BM = 64, BN = 64, BK = 32;
    __shared__ float As[BK][BM + 4];   // transposed: As[k][m]
    __shared__ float Ws[BK][BN + 4];

    const int tid = threadIdx.x;
    const int tx  = tid & 15;          // 0..15 (cols)
    const int ty  = tid >> 4;          // 0..15 (rows)
    const int m0  = blockIdx.x * BM;
    const int n0  = blockIdx.y * BN;

    float acc[4][4] = {};

    for (int k0 = 0; k0 < K; k0 += BK) {
        {
            int r  = tid >> 3;               // 0..31
            int c4 = (tid & 7) * 4;          // 0..28
#pragma unroll
            for (int h = 0; h < 2; ++h) {
                int rr = r + h * 32;
                float4 v = *(const float4*)&A[(size_t)(m0 + rr) * K + k0 + c4];
                As[c4 + 0][rr] = v.x; As[c4 + 1][rr] = v.y;
                As[c4 + 2][rr] = v.z; As[c4 + 3][rr] = v.w;
            }
        }
        {
            int r  = tid >> 4;               // 0..15
            int c4 = (tid & 15) * 4;         // 0..60
#pragma unroll
            for (int h = 0; h < 2; ++h) {
                int rr = r + h * 16;
                float4 v = *(const float4*)&W[(size_t)(k0 + rr) * N + n0 + c4];
                *(float4*)&Ws[rr][c4] = v;
            }
        }
        __syncthreads();

#pragma unroll
        for (int kk = 0; kk < BK; ++kk) {
            float4 a = *(const float4*)&As[kk][ty * 4];
            float4 b = *(const float4*)&Ws[kk][tx * 4];
            float av[4] = {a.x, a.y, a.z, a.w};
            float bv[4] = {b.x, b.y, b.z, b.w};
#pragma unroll
            for (int i = 0; i < 4; ++i)
#pragma unroll
                for (int j = 0; j < 4; ++j)
                    acc[i][j] = fmaf(av[i], bv[j], acc[i][j]);
        }
        __syncthreads();
    }

    float bv[4];
#pragma unroll
    for (int j = 0; j < 4; ++j) bv[j] = bias[n0 + tx * 4 + j];

#pragma unroll
    for (int i = 0; i < 4; ++i) {
        float c[4];
#pragma unroll
        for (int j = 0; j < 4; ++j) {
            c[j] = acc[i][j] + bv[j];
            if (RELU) c[j] = fmaxf(c[j], 0.0f);
        }
        if (LN) {
            float s  = c[0] + c[1] + c[2] + c[3];
            float ss = c[0]*c[0] + c[1]*c[1] + c[2]*c[2] + c[3]*c[3];
#pragma unroll
            for (int m = 1; m <= 8; m <<= 1) {
                s  += __shfl_xor(s,  m, 64);
                ss += __shfl_xor(ss, m, 64);
            }
            float mean = s * (1.0f / 64.0f);
            float var  = ss * (1.0f / 64.0f) - mean * mean;
            float rstd = rsqrtf(var + EPS);
#pragma unroll
            for (int j = 0; j < 4; ++j) c[j] = (c[j] - mean) * rstd;
        }
        size_t row = (size_t)(m0 + ty * 4 + i);
        *(float4*)&C[row * N + n0 + tx * 4] = make_float4(c[0], c[1], c[2], c[3]);
        if (ZP) {
            // token = row*8 + n0/64 (BN=64 spans exactly one token), dims tx*4..+3
            u16 hs[4] __attribute__((aligned(8)));
            u16 ls[4] __attribute__((aligned(8)));
            split2(c[0], hs[0], ls[0]); split2(c[1], hs[1], ls[1]);
            split2(c[2], hs[2], ls[2]); split2(c[3], hs[3], ls[3]);
            size_t tokoff = ((size_t)row * 8 + (n0 >> 6)) * CDIM + tx * 4;
            *(uint2*)&zph[tokoff] = *(const uint2*)hs;
            *(uint2*)&zpl[tokoff] = *(const uint2*)ls;
        }
    }
}

// ---------------------------------------------------------------------------
// DECODER GEMM2: split-bf16 MFMA GEMM (3-pass), pre-split planes [proven R5]
// ---------------------------------------------------------------------------
__launch_bounds__(256, 2)
__global__ void gemm_split(const u16* __restrict__ Ahi, const u16* __restrict__ Alo,
                           const u16* __restrict__ Bhi, const u16* __restrict__ Blo,
                           const float* __restrict__ bias,
                           float* __restrict__ Of,
                           int M, int N, int K)
{
    constexpr int BM = 128;
    __shared__ uint4 As[2][BM * 4];
    __shared__ uint4 Bs[2][128 * 4];

    const int tid = threadIdx.x;
    const int wid = tid >> 6, l = tid & 63, ln = l & 15, kg = l >> 4;
    const int mw = wid >> 1, nw = wid & 1;
    const int m0 = blockIdx.x * BM, n0 = blockIdx.y * 128;
    const int swz = (ln >> 1) & 3;

    f32x4 acc[4][4];
#pragma unroll
    for (int i = 0; i < 4; ++i)
#pragma unroll
        for (int j = 0; j < 4; ++j) acc[i][j] = (f32x4){0.f, 0.f, 0.f, 0.f};

    uint4 ra[4], rb[4];
    auto gload = [&](int k0){
#pragma unroll
        for (int h = 0; h < 4; ++h){
            int idx = tid + 256 * h; int r = idx >> 3, pl = (idx >> 2) & 1, c = idx & 3;
            ra[h] = *(const uint4*)((pl ? Alo : Ahi) + (size_t)(m0 + r) * K + k0 + c * 8);
        }
#pragma unroll
        for (int h = 0; h < 4; ++h){
            int idx = tid + 256 * h; int r = idx >> 3, pl = (idx >> 2) & 1, c = idx & 3;
            rb[h] = *(const uint4*)((pl ? Blo : Bhi) + (size_t)(n0 + r) * K + k0 + c * 8);
        }
    };
    auto lstore = [&](){
#pragma unroll
        for (int h = 0; h < 4; ++h){
            int idx = tid + 256 * h; int r = idx >> 3, pl = (idx >> 2) & 1, c = idx & 3;
            As[pl][r * 4 + (c ^ ((r >> 1) & 3))] = ra[h];
        }
#pragma unroll
        for (int h = 0; h < 4; ++h){
            int idx = tid + 256 * h; int r = idx >> 3, pl = (idx >> 2) & 1, c = idx & 3;
            Bs[pl][r * 4 + (c ^ ((r >> 1) & 3))] = rb[h];
        }
    };

    gload(0);
    for (int k0 = 0; k0 < K; k0 += 32){
        if (k0) __syncthreads();
        lstore();
        __syncthreads();
        if (k0 + 32 < K) gload(k0 + 32);

        bf16x8 af[4][2], bfr[4][2];
#pragma unroll
        for (int mi = 0; mi < 4; ++mi){
            int r = mw * 64 + mi * 16 + ln;
            af[mi][0] = *(bf16x8*)&As[0][r * 4 + (kg ^ swz)];
            af[mi][1] = *(bf16x8*)&As[1][r * 4 + (kg ^ swz)];
        }
#pragma unroll
        for (int ni = 0; ni < 4; ++ni){
            int r = nw * 64 + ni * 16 + ln;
            bfr[ni][0] = *(bf16x8*)&Bs[0][r * 4 + (kg ^ swz)];
            bfr[ni][1] = *(bf16x8*)&Bs[1][r * 4 + (kg ^ swz)];
        }
#pragma unroll
        for (int mi = 0; mi < 4; ++mi)
#pragma unroll
            for (int ni = 0; ni < 4; ++ni){
                acc[mi][ni] = MFMA16(af[mi][0], bfr[ni][0], acc[mi][ni]);
                acc[mi][ni] = MFMA16(af[mi][0], bfr[ni][1], acc[mi][ni]);
                acc[mi][ni] = MFMA16(af[mi][1], bfr[ni][0], acc[mi][ni]);
            }
    }

    float bv[4];
#pragma unroll
    for (int ni = 0; ni < 4; ++ni) bv[ni] = bias[n0 + nw * 64 + ni * 16 + ln];
#pragma unroll
    for (int mi = 0; mi < 4; ++mi)
#pragma unroll
        for (int r = 0; r < 4; ++r){
            size_t row = (size_t)(m0 + mw * 64 + mi * 16 + kg * 4 + r);
#pragma unroll
            for (int ni = 0; ni < 4; ++ni)
                Of[row * N + n0 + nw * 64 + ni * 16 + ln] = acc[mi][ni][r] + bv[ni];
        }
}

// ---------------------------------------------------------------------------
// VQ v6: 1024 blocks x 256 thr (4 waves, 3 blocks/CU). Each wave owns 32
// tokens; a-frags loaded ONCE from pre-split z planes (global, in regs).
// Codebook in 4 block-staged chunks of 128 codes (32KB LDS, swz ch^(r&7)),
// register-prefetched; 7 barriers per block over 128 tokens (R2 had 8 per 64).
// Per-wave: 96 MFMAs/chunk, 384 total. Scoring/butterfly/rescue/tail all
// verbatim from R4's vq_mega (passed correctness). dist = c2[c] - 2*cross.
// ---------------------------------------------------------------------------
__launch_bounds__(256, 3)
__global__ void vq_v6(const u16* __restrict__ Zh, const u16* __restrict__ Zl,
                      const float* __restrict__ zf32,
                      const u16* __restrict__ Chi, const u16* __restrict__ Clo,
                      const float* __restrict__ cbf, const float* __restrict__ c2,
                      const float* __restrict__ Ptab, const float* __restrict__ db1,
                      float* __restrict__ zq_o, float* __restrict__ idx_o,
                      u16* __restrict__ h_h, u16* __restrict__ h_l)
{
    __shared__ uint4 Bz[2][128 * 8];    // 32KB: chunk of 128 codes, 2 planes
    __shared__ float c2s[NCODES];       // 2KB
    __shared__ int   fIw[4][32];        // per-wave final indices

    const int tid = threadIdx.x;
    const int wid = tid >> 6, l = tid & 63, ln = l & 15, kg = l >> 4;
    const int tok0 = blockIdx.x * 128 + wid * 32;   // this wave's 32 tokens

    uint4 rb[8];
    auto gload = [&](int c0){
#pragma unroll
        for (int h = 0; h < 8; ++h){
            int idx = tid + 256 * h;         // 0..2047 16B chunks
            int pl = idx >> 10, rem = idx & 1023, r = rem >> 3, ch = rem & 7;
            rb[h] = *(const uint4*)((pl ? Clo : Chi) + (size_t)(c0 + r) * CDIM + ch * 8);
        }
    };
    auto lstore = [&](){
#pragma unroll
        for (int h = 0; h < 8; ++h){
            int idx = tid + 256 * h;
            int pl = idx >> 10, rem = idx & 1023, r = rem >> 3, ch = rem & 7;
            Bz[pl][r * 8 + (ch ^ (r & 7))] = rb[h];
        }
    };

    gload(0);
    c2s[tid] = c2[tid]; c2s[tid + 256] = c2[tid + 256];

    // a-frags: direct from pre-split z planes (no LDS round-trip)
    bf16x8 a[2][2][2];   // [mi][ks][plane]
#pragma unroll
    for (int mi = 0; mi < 2; ++mi){
        const u16* ph  = Zh + (size_t)(tok0 + mi * 16 + ln) * CDIM + kg * 8;
        const u16* pl2 = Zl + (size_t)(tok0 + mi * 16 + ln) * CDIM + kg * 8;
        a[mi][0][0] = *(const bf16x8*)ph;
        a[mi][1][0] = *(const bf16x8*)(ph + 32);
        a[mi][0][1] = *(const bf16x8*)pl2;
        a[mi][1][1] = *(const bf16x8*)(pl2 + 32);
    }

    lstore();
    __syncthreads();

    float b1[2][4], b2[2][4]; int i1[2][4];
#pragma unroll
    for (int mi = 0; mi < 2; ++mi)
#pragma unroll
        for (int r = 0; r < 4; ++r){ b1[mi][r] = 3.4e38f; b2[mi][r] = 3.4e38f; i1[mi][r] = 0; }

    for (int cc = 0; cc < 4; ++cc){
        if (cc < 3) gload((cc + 1) * 128);   // prefetch next chunk into regs

#pragma unroll
        for (int ni = 0; ni < 8; ++ni){
            int r = ni * 16 + ln, sw = r & 7;
            bf16x8 b0h = *(const bf16x8*)&Bz[0][r * 8 + (kg ^ sw)];
            bf16x8 b1h = *(const bf16x8*)&Bz[0][r * 8 + ((4 + kg) ^ sw)];
            bf16x8 b0l = *(const bf16x8*)&Bz[1][r * 8 + (kg ^ sw)];
            bf16x8 b1l = *(const bf16x8*)&Bz[1][r * 8 + ((4 + kg) ^ sw)];

            f32x4 t0 = (f32x4){0.f,0.f,0.f,0.f}, t1 = (f32x4){0.f,0.f,0.f,0.f};
            t0 = MFMA16(a[0][0][0], b0h, t0);  t1 = MFMA16(a[1][0][0], b0h, t1);
            t0 = MFMA16(a[0][0][0], b0l, t0);  t1 = MFMA16(a[1][0][0], b0l, t1);
            t0 = MFMA16(a[0][0][1], b0h, t0);  t1 = MFMA16(a[1][0][1], b0h, t1);
            t0 = MFMA16(a[0][1][0], b1h, t0);  t1 = MFMA16(a[1][1][0], b1h, t1);
            t0 = MFMA16(a[0][1][0], b1l, t0);  t1 = MFMA16(a[1][1][0], b1l, t1);
            t0 = MFMA16(a[0][1][1], b1h, t0);  t1 = MFMA16(a[1][1][1], b1h, t1);

            int code = cc * 128 + ni * 16 + ln;       // ascending per lane
            float cv = c2s[code];
#pragma unroll
            for (int r4 = 0; r4 < 4; ++r4){
                float d = fmaf(-2.f, t0[r4], cv);
                if (d < b1[0][r4]) { b2[0][r4] = b1[0][r4]; b1[0][r4] = d; i1[0][r4] = code; }
                else if (d < b2[0][r4]) b2[0][r4] = d;
                float e = fmaf(-2.f, t1[r4], cv);
                if (e < b1[1][r4]) { b2[1][r4] = b1[1][r4]; b1[1][r4] = e; i1[1][r4] = code; }
                else if (e < b2[1][r4]) b2[1][r4] = e;
            }
        }
        if (cc < 3){
            __syncthreads();     // all waves done reading this chunk
            lstore();
            __syncthreads();     // next chunk visible
        }
    }

    // 16-lane butterfly per token (tie -> lower idx); margin mask collection
    u32 rmask = 0;
#pragma unroll
    for (int mi = 0; mi < 2; ++mi)
#pragma unroll
        for (int r = 0; r < 4; ++r){
            float v1 = b1[mi][r], v2 = b2[mi][r]; int ii = i1[mi][r];
#pragma unroll
            for (int mk = 1; mk <= 8; mk <<= 1){
                float o1 = __shfl_xor(v1, mk, 64), o2 = __shfl_xor(v2, mk, 64);
                int   oi = __shfl_xor(ii, mk, 64);
                float n2 = fminf(fmaxf(v1, o1), fminf(v2, o2));
                if (o1 < v1 || (o1 == v1 && oi < ii)){ v1 = o1; ii = oi; }
                v2 = n2;
            }
            if (ln == 0) fIw[wid][mi * 16 + kg * 4 + r] = ii;
            if (v2 - v1 < MARGIN) rmask |= 1u << (mi * 16 + kg * 4 + r);
        }
    rmask |= __shfl_xor(rmask, 16, 64);
    rmask |= __shfl_xor(rmask, 32, 64);

    // wave-local exact fp32 rescue (rare); lane handles 8 ascending codes
    while (rmask){
        int tk = __builtin_ctz(rmask); rmask &= rmask - 1;
        const float* zr = zf32 + (size_t)(tok0 + tk) * CDIM;
        float best = 3.4e38f; int bi = 0;
#pragma unroll
        for (int j = 0; j < 8; ++j){
            int c = l * 8 + j;
            const float* cp = cbf + (size_t)c * CDIM;
            float d0 = 0.f, d1 = 0.f, d2 = 0.f, d3 = 0.f;
#pragma unroll
            for (int d4 = 0; d4 < 16; ++d4){
                float4 zz = *(const float4*)(zr + d4 * 4);   // broadcast (uniform addr)
                float4 cc2 = *(const float4*)(cp + d4 * 4);
                d0 = fmaf(zz.x, cc2.x, d0); d1 = fmaf(zz.y, cc2.y, d1);
                d2 = fmaf(zz.z, cc2.z, d2); d3 = fmaf(zz.w, cc2.w, d3);
            }
            float d = fmaf(-2.f, (d0 + d1) + (d2 + d3), c2s[c]);
            if (d < best){ best = d; bi = c; }
        }
#pragma unroll
        for (int mk = 1; mk < 64; mk <<= 1){
            float o = __shfl_xor(best, mk, 64); int oi = __shfl_xor(bi, mk, 64);
            if (o < best || (o == best && oi < bi)){ best = o; bi = oi; }
        }
        if (l == 0) fIw[wid][tk] = bi;
    }
    // wave-internal LDS RAW fence (no block barrier needed)
    asm volatile("s_waitcnt lgkmcnt(0)" ::: "memory");
    __builtin_amdgcn_sched_barrier(0);

    // idx output (32 tokens)
    if (l < 32) idx_o[tok0 + l] = (float)fIw[wid][l];

    // zq output: lane pair per token, 32 dims each (exact fp32 codebook gather)
    {
        int tk = l >> 1, half = l & 1;
        int ii = fIw[wid][tk];
        const float* cf = cbf + (size_t)ii * CDIM + half * 32;
        float* zo = zq_o + (size_t)(tok0 + tk) * CDIM + half * 32;
#pragma unroll
        for (int q = 0; q < 8; ++q)
            *(float4*)(zo + q * 4) = *(const float4*)(cf + q * 4);
    }

    // fused decoder GEMM1: h = relu(b1 + sum_t P[idx_t][t][:]) for 4 samples
    {
        int sl = l >> 4, jj = (l & 15) * 8;
        int samp = (tok0 >> 3) + sl;
        float4 h0 = *(const float4*)&db1[jj];
        float4 h1 = *(const float4*)&db1[jj + 4];
#pragma unroll
        for (int t = 0; t < 8; ++t){
            int c = fIw[wid][sl * 8 + t];
            const float* pp = Ptab + ((size_t)c * 8 + t) * HID + jj;
            float4 p0 = *(const float4*)pp, p1 = *(const float4*)(pp + 4);
            h0.x += p0.x; h0.y += p0.y; h0.z += p0.z; h0.w += p0.w;
            h1.x += p1.x; h1.y += p1.y; h1.z += p1.z; h1.w += p1.w;
        }
        float hv[8] = {fmaxf(h0.x,0.f), fmaxf(h0.y,0.f), fmaxf(h0.z,0.f), fmaxf(h0.w,0.f),
                       fmaxf(h1.x,0.f), fmaxf(h1.y,0.f), fmaxf(h1.z,0.f), fmaxf(h1.w,0.f)};
        u16 hh[8] __attribute__((aligned(16)));
        u16 ll[8] __attribute__((aligned(16)));
#pragma unroll
        for (int q = 0; q < 8; ++q) split2(hv[q], hh[q], ll[q]);
        size_t hrow = (size_t)samp * HID + jj;
        *(uint4*)&h_h[hrow] = *(const uint4*)hh;
        *(uint4*)&h_l[hrow] = *(const uint4*)ll;
    }
}

// ---------------------------------------------------------------------------
extern "C" void kernel_launch(void* const* d_in, const int* in_sizes, int n_in,
                              void* d_out, int out_size, void* d_ws, size_t ws_size,
                              hipStream_t stream) {
    const float* x      = (const float*)d_in[0];
    const float* enc_w1 = (const float*)d_in[1];
    const float* enc_b1 = (const float*)d_in[2];
    const float* enc_w2 = (const float*)d_in[3];
    const float* enc_b2 = (const float*)d_in[4];
    const float* cbk    = (const float*)d_in[5];
    const float* dec_w1 = (const float*)d_in[6];
    const float* dec_b1 = (const float*)d_in[7];
    const float* dec_w2 = (const float*)d_in[8];
    const float* dec_b2 = (const float*)d_in[9];

    // outputs, all float32, concatenated flat: recon | z_q | indices
    float* out     = (float*)d_out;
    float* recon_o = out;
    float* zq_o    = out + (size_t)B_ * TD;
    float* idx_o   = out + 2 * (size_t)B_ * TD;

    // workspace carve-up
    float* zbuf  = (float*)d_ws;                        // [B,512] fp32 z (post-LN)
    float* hbuf  = zbuf + (size_t)B_ * TD;              // [B,128] fp32 enc hidden / dec h planes
    float* c2buf = hbuf + (size_t)B_ * HID;             // 512
    float* Ptab  = c2buf + 512;                         // 512*8*128 fp32 = 2MB
    u16* w = (u16*)(Ptab + (size_t)NCODES * NTOK * HID);
    u16* d2t_h = w; w += 65536;  u16* d2t_l = w; w += 65536;   // dec_w2^T [512][128]
    u16* cb_h  = w; w += 32768;  u16* cb_l  = w; w += 32768;   // codebook [512][64]
    u16* z_h   = w; w += (size_t)B_ * NTOK * CDIM;             // z planes [131072][64]
    u16* z_l   = w; w += (size_t)B_ * NTOK * CDIM;
    // decoder hidden planes alias hbuf (hbuf dead after enc2)
    u16* h_h = (u16*)hbuf;
    u16* h_l = h_h + (size_t)B_ * HID;

    // ---- preps ----
    hipLaunchKernelGGL(tsplit_kernel, dim3(256), dim3(256), 0, stream, dec_w2, d2t_h, d2t_l, TD, 7);
    hipLaunchKernelGGL(csplit_kernel, dim3(128), dim3(256), 0, stream, cbk, cb_h, cb_l);
    hipLaunchKernelGGL(c2_kernel, dim3(NCODES), dim3(64), 0, stream, cbk, c2buf);
    hipLaunchKernelGGL(pprep_kernel, dim3(NCODES, NTOK), dim3(HID), 0, stream, cbk, dec_w1, Ptab);

    // ---- encoder GEMM1 + ReLU (fp32 VALU): x @ w1 -> hbuf ----
    hipLaunchKernelGGL((gemm_kernel<true, false, false>), dim3(B_ / 64, HID / 64), dim3(256), 0,
                       stream, x, enc_w1, enc_b1, hbuf, (u16*)nullptr, (u16*)nullptr,
                       B_, HID, TD);

    // ---- encoder GEMM2 + LN (fp32 VALU): hbuf @ w2 -> zbuf (+ z planes) ----
    hipLaunchKernelGGL((gemm_kernel<false, true, true>), dim3(B_ / 64, LAT / 64), dim3(256), 0,
                       stream, hbuf, enc_w2, enc_b2, zbuf, z_h, z_l,
                       B_, LAT, HID);

    // ---- VQ v6 (MFMA argmin + rescue + zq/idx + h planes) ----
    hipLaunchKernelGGL(vq_v6, dim3(B_ * NTOK / 128), dim3(256), 0, stream,
                       z_h, z_l, zbuf, cb_h, cb_l, cbk, c2buf, Ptab, dec_b1,
                       zq_o, idx_o, h_h, h_l);

    // ---- decoder GEMM2 (MFMA): h planes @ dw2 -> recon fp32 ----
    hipLaunchKernelGGL(gemm_split, dim3(B_ / 128, TD / 128), dim3(256), 0, stream,
                       h_h, h_l, d2t_h, d2t_l, dec_b2, recon_o, B_, TD, HID);
}

// Round 7
// 300.642 us; speedup vs baseline: 1.4051x; 1.3255x over previous
//
#include <hip/hip_runtime.h>

// Problem constants
#define B_     16384
#define TD     512     // T*D
#define HID    128
#define LAT    512     // N_TOKENS*CODE_DIM
#define NCODES 512
#define CDIM   64
#define NTOK   8
#define EPS    1e-5f
#define MARGIN 0.02f   // ~10x worst-case approx-distance error (2.6e-3) post-LN

typedef unsigned short u16;
typedef unsigned int   u32;
typedef short bf16x8 __attribute__((ext_vector_type(8)));   // 8 bf16 = 4 VGPR (MFMA A/B frag)
typedef float f32x4  __attribute__((ext_vector_type(4)));   // MFMA C/D frag

__device__ __forceinline__ u16 bf16_rn(float f){
    u32 u = __float_as_uint(f);
    return (u16)((u + 0x7fffu + ((u >> 16) & 1u)) >> 16);   // round-nearest-even
}
__device__ __forceinline__ float bf16_f(u16 h){ return __uint_as_float(((u32)h) << 16); }
__device__ __forceinline__ void split2(float f, u16& hi, u16& lo){
    hi = bf16_rn(f);
    lo = bf16_rn(f - bf16_f(hi));     // residual: |a - hi - lo| <= ~2^-18 |a|
}
#define MFMA16(a,b,c) __builtin_amdgcn_mfma_f32_16x16x32_bf16((a),(b),(c),0,0,0)

// ---------------------------------------------------------------------------
// Prep: c2[c] = ||codebook[c]||^2 (fp32 exact)
// ---------------------------------------------------------------------------
__global__ void c2_kernel(const float* __restrict__ cb, float* __restrict__ c2) {
    int c = blockIdx.x;
    int d = threadIdx.x;            // 64 threads = 1 wave
    float v = cb[c * CDIM + d];
    float s = v * v;
#pragma unroll
    for (int m = 32; m >= 1; m >>= 1) s += __shfl_xor(s, m, 64);
    if (d == 0) c2[c] = s;
}

// ---------------------------------------------------------------------------
// Prep: transpose+split W[K][N] -> hi/lo planes [N][K] (bf16)
// ---------------------------------------------------------------------------
__global__ void tsplit_kernel(const float* __restrict__ W, u16* __restrict__ hi,
                              u16* __restrict__ lo, int N, int kshift){
    int id = blockIdx.x * 256 + threadIdx.x;    // over N*K output elems
    int K = 1 << kshift;
    int n = id >> kshift, k = id & (K - 1);
    u16 h, l2; split2(W[(size_t)k * N + n], h, l2);
    hi[id] = h; lo[id] = l2;
}
// Prep: split codebook [512][64] (no transpose)
__global__ void csplit_kernel(const float* __restrict__ C, u16* __restrict__ hi,
                              u16* __restrict__ lo){
    int id = blockIdx.x * 256 + threadIdx.x;
    u16 h, l2; split2(C[id], h, l2);
    hi[id] = h; lo[id] = l2;
}
// Prep: P[c][t][j] = sum_k cb[c][k] * dec_w1[t*64+k][j]   (replaces dec GEMM1)
__global__ void pprep_kernel(const float* __restrict__ cb, const float* __restrict__ dw1,
                             float* __restrict__ P){
    int c = blockIdx.x, t = blockIdx.y, j = threadIdx.x;
    const float* wp = dw1 + (size_t)t * 64 * HID + j;
    const float* cp = cb + (size_t)c * CDIM;
    float acc = 0.f;
#pragma unroll
    for (int k = 0; k < 64; ++k) acc = fmaf(cp[k], wp[(size_t)k * HID], acc);
    P[((size_t)c * 8 + t) * HID + j] = acc;
}

// ---------------------------------------------------------------------------
// ENCODER PATH (fp32 reference numerics class): baseline VALU fp32 tiled GEMM.
// [byte-identical to the R2 kernel that measured 317.8us total — do not touch]
// ---------------------------------------------------------------------------
template<bool RELU, bool LN>
__launch_bounds__(256)
__global__ void gemm_kernel(const float* __restrict__ A, const float* __restrict__ W,
                            const float* __restrict__ bias,
                            float* __restrict__ C,
                            int M, int N, int K) {
    constexpr int BM = 64, BN = 64, BK = 32;
    __shared__ float As[BK][BM + 4];   // transposed: As[k][m]
    __shared__ float Ws[BK][BN + 4];

    const int tid = threadIdx.x;
    const int tx  = tid & 15;          // 0..15 (cols)
    const int ty  = tid >> 4;          // 0..15 (rows)
    const int m0  = blockIdx.x * BM;
    const int n0  = blockIdx.y * BN;

    float acc[4][4] = {};

    for (int k0 = 0; k0 < K; k0 += BK) {
        {
            int r  = tid >> 3;               // 0..31
            int c4 = (tid & 7) * 4;          // 0..28
#pragma unroll
            for (int h = 0; h < 2; ++h) {
                int rr = r + h * 32;
                float4 v = *(const float4*)&A[(size_t)(m0 + rr) * K + k0 + c4];
                As[c4 + 0][rr] = v.x; As[c4 + 1][rr] = v.y;
                As[c4 + 2][rr] = v.z; As[c4 + 3][rr] = v.w;
            }
        }
        {
            int r  = tid >> 4;               // 0..15
            int c4 = (tid & 15) * 4;         // 0..60
#pragma unroll
            for (int h = 0; h < 2; ++h) {
                int rr = r + h * 16;
                float4 v = *(const float4*)&W[(size_t)(k0 + rr) * N + n0 + c4];
                *(float4*)&Ws[rr][c4] = v;
            }
        }
        __syncthreads();

#pragma unroll
        for (int kk = 0; kk < BK; ++kk) {
            float4 a = *(const float4*)&As[kk][ty * 4];
            float4 b = *(const float4*)&Ws[kk][tx * 4];
            float av[4] = {a.x, a.y, a.z, a.w};
            float bv[4] = {b.x, b.y, b.z, b.w};
#pragma unroll
            for (int i = 0; i < 4; ++i)
#pragma unroll
                for (int j = 0; j < 4; ++j)
                    acc[i][j] = fmaf(av[i], bv[j], acc[i][j]);
        }
        __syncthreads();
    }

    float bv[4];
#pragma unroll
    for (int j = 0; j < 4; ++j) bv[j] = bias[n0 + tx * 4 + j];

#pragma unroll
    for (int i = 0; i < 4; ++i) {
        float c[4];
#pragma unroll
        for (int j = 0; j < 4; ++j) {
            c[j] = acc[i][j] + bv[j];
            if (RELU) c[j] = fmaxf(c[j], 0.0f);
        }
        if (LN) {
            float s  = c[0] + c[1] + c[2] + c[3];
            float ss = c[0]*c[0] + c[1]*c[1] + c[2]*c[2] + c[3]*c[3];
#pragma unroll
            for (int m = 1; m <= 8; m <<= 1) {
                s  += __shfl_xor(s,  m, 64);
                ss += __shfl_xor(ss, m, 64);
            }
            float mean = s * (1.0f / 64.0f);
            float var  = ss * (1.0f / 64.0f) - mean * mean;
            float rstd = rsqrtf(var + EPS);
#pragma unroll
            for (int j = 0; j < 4; ++j) c[j] = (c[j] - mean) * rstd;
        }
        size_t row = (size_t)(m0 + ty * 4 + i);
        *(float4*)&C[row * N + n0 + tx * 4] = make_float4(c[0], c[1], c[2], c[3]);
    }
}

// ---------------------------------------------------------------------------
// DECODER GEMM2: split-bf16 MFMA GEMM (3-pass), pre-split planes [proven R5/R6]
// ---------------------------------------------------------------------------
__launch_bounds__(256, 2)
__global__ void gemm_split(const u16* __restrict__ Ahi, const u16* __restrict__ Alo,
                           const u16* __restrict__ Bhi, const u16* __restrict__ Blo,
                           const float* __restrict__ bias,
                           float* __restrict__ Of,
                           int M, int N, int K)
{
    constexpr int BM = 128;
    __shared__ uint4 As[2][BM * 4];
    __shared__ uint4 Bs[2][128 * 4];

    const int tid = threadIdx.x;
    const int wid = tid >> 6, l = tid & 63, ln = l & 15, kg = l >> 4;
    const int mw = wid >> 1, nw = wid & 1;
    const int m0 = blockIdx.x * BM, n0 = blockIdx.y * 128;
    const int swz = (ln >> 1) & 3;

    f32x4 acc[4][4];
#pragma unroll
    for (int i = 0; i < 4; ++i)
#pragma unroll
        for (int j = 0; j < 4; ++j) acc[i][j] = (f32x4){0.f, 0.f, 0.f, 0.f};

    uint4 ra[4], rb[4];
    auto gload = [&](int k0){
#pragma unroll
        for (int h = 0; h < 4; ++h){
            int idx = tid + 256 * h; int r = idx >> 3, pl = (idx >> 2) & 1, c = idx & 3;
            ra[h] = *(const uint4*)((pl ? Alo : Ahi) + (size_t)(m0 + r) * K + k0 + c * 8);
        }
#pragma unroll
        for (int h = 0; h < 4; ++h){
            int idx = tid + 256 * h; int r = idx >> 3, pl = (idx >> 2) & 1, c = idx & 3;
            rb[h] = *(const uint4*)((pl ? Blo : Bhi) + (size_t)(n0 + r) * K + k0 + c * 8);
        }
    };
    auto lstore = [&](){
#pragma unroll
        for (int h = 0; h < 4; ++h){
            int idx = tid + 256 * h; int r = idx >> 3, pl = (idx >> 2) & 1, c = idx & 3;
            As[pl][r * 4 + (c ^ ((r >> 1) & 3))] = ra[h];
        }
#pragma unroll
        for (int h = 0; h < 4; ++h){
            int idx = tid + 256 * h; int r = idx >> 3, pl = (idx >> 2) & 1, c = idx & 3;
            Bs[pl][r * 4 + (c ^ ((r >> 1) & 3))] = rb[h];
        }
    };

    gload(0);
    for (int k0 = 0; k0 < K; k0 += 32){
        if (k0) __syncthreads();
        lstore();
        __syncthreads();
        if (k0 + 32 < K) gload(k0 + 32);

        bf16x8 af[4][2], bfr[4][2];
#pragma unroll
        for (int mi = 0; mi < 4; ++mi){
            int r = mw * 64 + mi * 16 + ln;
            af[mi][0] = *(bf16x8*)&As[0][r * 4 + (kg ^ swz)];
            af[mi][1] = *(bf16x8*)&As[1][r * 4 + (kg ^ swz)];
        }
#pragma unroll
        for (int ni = 0; ni < 4; ++ni){
            int r = nw * 64 + ni * 16 + ln;
            bfr[ni][0] = *(bf16x8*)&Bs[0][r * 4 + (kg ^ swz)];
            bfr[ni][1] = *(bf16x8*)&Bs[1][r * 4 + (kg ^ swz)];
        }
#pragma unroll
        for (int mi = 0; mi < 4; ++mi)
#pragma unroll
            for (int ni = 0; ni < 4; ++ni){
                acc[mi][ni] = MFMA16(af[mi][0], bfr[ni][0], acc[mi][ni]);
                acc[mi][ni] = MFMA16(af[mi][0], bfr[ni][1], acc[mi][ni]);
                acc[mi][ni] = MFMA16(af[mi][1], bfr[ni][0], acc[mi][ni]);
            }
    }

    float bv[4];
#pragma unroll
    for (int ni = 0; ni < 4; ++ni) bv[ni] = bias[n0 + nw * 64 + ni * 16 + ln];
#pragma unroll
    for (int mi = 0; mi < 4; ++mi)
#pragma unroll
        for (int r = 0; r < 4; ++r){
            size_t row = (size_t)(m0 + mw * 64 + mi * 16 + kg * 4 + r);
#pragma unroll
            for (int ni = 0; ni < 4; ++ni)
                Of[row * N + n0 + nw * 64 + ni * 16 + ln] = acc[mi][ni][r] + bv[ni];
        }
}

// ---------------------------------------------------------------------------
// VQ (R2's proven vq_kernel2, 107.8us) with two surgical edits:
//   - zq_ws store removed (no consumer: dec GEMM1 is replaced by P-table)
//   - P-table h-gather tail appended (proven in R3-R6), writes h planes
// Everything else byte-identical: block = 64 tokens, 4 waves; z staged in LDS;
// codebook in 4 chunks of 128 codes; 3-pass scoring; strict-< ascending scan;
// 16-lane butterfly; MARGIN + exact-fp32 rescue.
// ---------------------------------------------------------------------------
__launch_bounds__(256, 2)
__global__ void vq_kernel3(const float* __restrict__ zln,
                           const u16* __restrict__ Chi, const u16* __restrict__ Clo,
                           const float* __restrict__ cbf, const float* __restrict__ c2,
                           const float* __restrict__ Ptab, const float* __restrict__ db1,
                           float* __restrict__ zq_o, float* __restrict__ idx_o,
                           u16* __restrict__ h_h, u16* __restrict__ h_l)
{
    __shared__ uint4 Az[2][64 * 8];     // z tile planes, swizzle ch ^ (row&7)
    __shared__ uint4 Bz[2][128 * 8];    // codebook chunk planes
    __shared__ float c2s[512];
    __shared__ float cB1[4][64], cB2[4][64];
    __shared__ int   cI1[4][64];
    __shared__ int   fI[64];
    __shared__ float zf[64];
    __shared__ int   nflag;
    __shared__ int   flagR[64];
    __shared__ float wB[4];
    __shared__ int   wI[4];

    const int tid = threadIdx.x;
    const int wid = tid >> 6, l = tid & 63, ln = l & 15, kg = l >> 4;
    const int m0 = blockIdx.x * 64;

    // stage z tile: on-the-fly fp32 -> bf16 hi/lo split
#pragma unroll
    for (int h = 0; h < 4; ++h){
        int idx = tid + 256 * h;         // 1024 quarter-rows of 4 dims
        int r = idx >> 4, q = idx & 15;
        float4 v = *(const float4*)&zln[(size_t)(m0 + r) * CDIM + q * 4];
        u16 hs[4] __attribute__((aligned(8)));
        u16 ls[4] __attribute__((aligned(8)));
        split2(v.x, hs[0], ls[0]); split2(v.y, hs[1], ls[1]);
        split2(v.z, hs[2], ls[2]); split2(v.w, hs[3], ls[3]);
        int c = q >> 1, half = q & 1;
        int ch = c ^ (r & 7);
        ((uint2*)&Az[0][r * 8 + ch])[half] = *(const uint2*)hs;
        ((uint2*)&Az[1][r * 8 + ch])[half] = *(const uint2*)ls;
    }
    c2s[tid] = c2[tid]; c2s[tid + 256] = c2[tid + 256];
    if (tid == 0) nflag = 0;
    // stage codebook chunk 0
#pragma unroll
    for (int h = 0; h < 8; ++h){
        int idx = tid + 256 * h; int r = idx >> 4, pl = (idx >> 3) & 1, c = idx & 7;
        const u16* p = (pl ? Clo : Chi) + (size_t)r * CDIM + c * 8;
        Bz[pl][r * 8 + (c ^ (r & 7))] = *(const uint4*)p;
    }
    __syncthreads();

    // A fragments (held in registers for all chunks)
    bf16x8 a[4][2][2];                  // [mi][kslice][plane]
#pragma unroll
    for (int mi = 0; mi < 4; ++mi){
        int r = mi * 16 + ln;
#pragma unroll
        for (int ks = 0; ks < 2; ++ks){
            int c = ks * 4 + kg;
            a[mi][ks][0] = *(bf16x8*)&Az[0][r * 8 + (c ^ (r & 7))];
            a[mi][ks][1] = *(bf16x8*)&Az[1][r * 8 + (c ^ (r & 7))];
        }
    }

    float b1[4][4], b2[4][4]; int i1[4][4];
#pragma unroll
    for (int mi = 0; mi < 4; ++mi)
#pragma unroll
        for (int r = 0; r < 4; ++r){ b1[mi][r] = 3.4e38f; b2[mi][r] = 3.4e38f; i1[mi][r] = 0; }

    for (int cc = 0; cc < 4; ++cc){
        bf16x8 b[2][2][2];
#pragma unroll
        for (int ni = 0; ni < 2; ++ni){
            int r = wid * 32 + ni * 16 + ln;
#pragma unroll
            for (int ks = 0; ks < 2; ++ks){
                int c = ks * 4 + kg;
                b[ni][ks][0] = *(bf16x8*)&Bz[0][r * 8 + (c ^ (r & 7))];
                b[ni][ks][1] = *(bf16x8*)&Bz[1][r * 8 + (c ^ (r & 7))];
            }
        }
        f32x4 acc[4][2];
#pragma unroll
        for (int mi = 0; mi < 4; ++mi)
#pragma unroll
            for (int ni = 0; ni < 2; ++ni) acc[mi][ni] = (f32x4){0.f, 0.f, 0.f, 0.f};
#pragma unroll
        for (int mi = 0; mi < 4; ++mi)
#pragma unroll
            for (int ni = 0; ni < 2; ++ni)
#pragma unroll
                for (int ks = 0; ks < 2; ++ks){
                    acc[mi][ni] = MFMA16(a[mi][ks][0], b[ni][ks][0], acc[mi][ni]);
                    acc[mi][ni] = MFMA16(a[mi][ks][0], b[ni][ks][1], acc[mi][ni]);
                    acc[mi][ni] = MFMA16(a[mi][ks][1], b[ni][ks][0], acc[mi][ni]);
                }
#pragma unroll
        for (int mi = 0; mi < 4; ++mi)
#pragma unroll
            for (int ni = 0; ni < 2; ++ni){
                int code = cc * 128 + wid * 32 + ni * 16 + ln;
#pragma unroll
                for (int r = 0; r < 4; ++r){
                    float d = fmaf(-2.f, acc[mi][ni][r], c2s[code]);
                    if (d < b1[mi][r]) { b2[mi][r] = b1[mi][r]; b1[mi][r] = d; i1[mi][r] = code; }
                    else if (d < b2[mi][r]) b2[mi][r] = d;
                }
            }
        if (cc < 3){
            __syncthreads();
#pragma unroll
            for (int h = 0; h < 8; ++h){
                int idx = tid + 256 * h; int r = idx >> 4, pl = (idx >> 3) & 1, c = idx & 7;
                const u16* p = (pl ? Clo : Chi) + (size_t)((cc + 1) * 128 + r) * CDIM + c * 8;
                Bz[pl][r * 8 + (c ^ (r & 7))] = *(const uint4*)p;
            }
            __syncthreads();
        }
    }

    // butterfly over the 16 lanes holding a row's columns (tie -> lower idx)
#pragma unroll
    for (int mi = 0; mi < 4; ++mi)
#pragma unroll
        for (int r = 0; r < 4; ++r){
            float v1 = b1[mi][r], v2 = b2[mi][r]; int ii = i1[mi][r];
#pragma unroll
            for (int mk = 1; mk <= 8; mk <<= 1){
                float o1 = __shfl_xor(v1, mk, 64), o2 = __shfl_xor(v2, mk, 64);
                int   oi = __shfl_xor(ii, mk, 64);
                float n2 = fminf(fmaxf(v1, o1), fminf(v2, o2));   // 2nd-smallest of union
                if (o1 < v1 || (o1 == v1 && oi < ii)){ v1 = o1; ii = oi; }
                v2 = n2;
            }
            if (ln == 0){
                int row = mi * 16 + kg * 4 + r;
                cB1[wid][row] = v1; cB2[wid][row] = v2; cI1[wid][row] = ii;
            }
        }
    __syncthreads();
    if (tid < 64){
        float v1 = cB1[0][tid], v2 = cB2[0][tid]; int ii = cI1[0][tid];
#pragma unroll
        for (int w = 1; w < 4; ++w){
            float o1 = cB1[w][tid], o2 = cB2[w][tid]; int oi = cI1[w][tid];
            float n2 = fminf(fmaxf(v1, o1), fminf(v2, o2));
            if (o1 < v1 || (o1 == v1 && oi < ii)){ v1 = o1; ii = oi; }
            v2 = n2;
        }
        fI[tid] = ii;
        if (v2 - v1 < MARGIN){ int s = atomicAdd(&nflag, 1); flagR[s] = tid; }
    }
    __syncthreads();

    // exact fp32 rescue for ambiguous tokens (reads true fp32 z)
    int nf = nflag;
    for (int f = 0; f < nf; ++f){
        int row = flagR[f];
        if (tid < 64) zf[tid] = zln[(size_t)(m0 + row) * CDIM + tid];
        __syncthreads();
        float bb = 3.4e38f; int bi = 0;
#pragma unroll
        for (int cH = 0; cH < 2; ++cH){
            int cc = tid + 256 * cH;
            const float* cp = cbf + (size_t)cc * CDIM;
            float dot = 0.f;
#pragma unroll
            for (int dd = 0; dd < 64; ++dd) dot = fmaf(zf[dd], cp[dd], dot);
            float d = fmaf(-2.f, dot, c2s[cc]);
            if (d < bb){ bb = d; bi = cc; }     // cc strictly ascending per thread
        }
#pragma unroll
        for (int mk = 1; mk < 64; mk <<= 1){
            float o = __shfl_xor(bb, mk, 64); int oi = __shfl_xor(bi, mk, 64);
            if (o < bb || (o == bb && oi < bi)){ bb = o; bi = oi; }
        }
        if (l == 0){ wB[wid] = bb; wI[wid] = bi; }
        __syncthreads();
        if (tid == 0){
            float v1 = wB[0]; int ii = wI[0];
#pragma unroll
            for (int w = 1; w < 4; ++w)
                if (wB[w] < v1 || (wB[w] == v1 && wI[w] < ii)){ v1 = wB[w]; ii = wI[w]; }
            fI[row] = ii;
        }
        __syncthreads();
    }

    // gather + outputs: 4 threads per row, 16 dims each (fp32, exact)
    {
        int row = tid >> 2, part = tid & 3;
        int ii  = fI[row];
        size_t gr = (size_t)(m0 + row);
        const float* cf = cbf + (size_t)ii * CDIM + part * 16;
        float4 q0 = *(const float4*)(cf + 0),  q1 = *(const float4*)(cf + 4);
        float4 q2 = *(const float4*)(cf + 8),  q3 = *(const float4*)(cf + 12);
        float* zo = zq_o + gr * CDIM + part * 16;
        *(float4*)(zo + 0) = q0; *(float4*)(zo + 4)  = q1;
        *(float4*)(zo + 8) = q2; *(float4*)(zo + 12) = q3;
        if (part == 0) idx_o[gr] = (float)ii;
    }

    // fused decoder GEMM1 via P-table: h = relu(b1 + sum_t P[idx_t][t][:])
    // block = samples blockIdx.x*8 .. +7; 32 threads per sample, 4 cols each
    {
        int s  = tid >> 5;                 // 0..7
        int j0 = (tid & 31) * 4;           // 0..124
        float4 hv = *(const float4*)&db1[j0];
#pragma unroll
        for (int t = 0; t < 8; ++t){
            int c = fI[s * 8 + t];
            const float* pp = Ptab + ((size_t)c * 8 + t) * HID + j0;
            float4 p = *(const float4*)pp;
            hv.x += p.x; hv.y += p.y; hv.z += p.z; hv.w += p.w;
        }
        hv.x = fmaxf(hv.x, 0.f); hv.y = fmaxf(hv.y, 0.f);
        hv.z = fmaxf(hv.z, 0.f); hv.w = fmaxf(hv.w, 0.f);
        u16 hh[4] __attribute__((aligned(8)));
        u16 ll[4] __attribute__((aligned(8)));
        split2(hv.x, hh[0], ll[0]); split2(hv.y, hh[1], ll[1]);
        split2(hv.z, hh[2], ll[2]); split2(hv.w, hh[3], ll[3]);
        size_t hrow = ((size_t)blockIdx.x * 8 + s) * HID + j0;
        *(uint2*)&h_h[hrow] = *(const uint2*)hh;
        *(uint2*)&h_l[hrow] = *(const uint2*)ll;
    }
}

// ---------------------------------------------------------------------------
extern "C" void kernel_launch(void* const* d_in, const int* in_sizes, int n_in,
                              void* d_out, int out_size, void* d_ws, size_t ws_size,
                              hipStream_t stream) {
    const float* x      = (const float*)d_in[0];
    const float* enc_w1 = (const float*)d_in[1];
    const float* enc_b1 = (const float*)d_in[2];
    const float* enc_w2 = (const float*)d_in[3];
    const float* enc_b2 = (const float*)d_in[4];
    const float* cbk    = (const float*)d_in[5];
    const float* dec_w1 = (const float*)d_in[6];
    const float* dec_b1 = (const float*)d_in[7];
    const float* dec_w2 = (const float*)d_in[8];
    const float* dec_b2 = (const float*)d_in[9];

    // outputs, all float32, concatenated flat: recon | z_q | indices
    float* out     = (float*)d_out;
    float* recon_o = out;
    float* zq_o    = out + (size_t)B_ * TD;
    float* idx_o   = out + 2 * (size_t)B_ * TD;

    // workspace carve-up
    float* zbuf  = (float*)d_ws;                       // [B,512] fp32 z (post-LN)
    float* hbuf  = zbuf + (size_t)B_ * TD;             // [B,128] fp32 enc hidden / dec h planes
    float* c2buf = hbuf + (size_t)B_ * HID;            // 512 fp32
    float* Ptab  = c2buf + 512;                        // 512*8*128 fp32 = 2 MB
    u16* w = (u16*)(Ptab + (size_t)NCODES * NTOK * HID);
    u16* d2t_h = w; w += 65536;   u16* d2t_l = w; w += 65536;   // dec_w2^T [512][128]
    u16* cb_h  = w; w += 32768;   u16* cb_l  = w; w += 32768;   // codebook [512][64]
    // decoder hidden planes alias hbuf (hbuf dead after encoder GEMM2)
    u16* h_h = (u16*)hbuf;
    u16* h_l = h_h + (size_t)B_ * HID;

    // ---- preps ----
    hipLaunchKernelGGL(tsplit_kernel, dim3(256), dim3(256), 0, stream, dec_w2, d2t_h, d2t_l, TD, 7);
    hipLaunchKernelGGL(csplit_kernel, dim3(128), dim3(256), 0, stream, cbk, cb_h, cb_l);
    hipLaunchKernelGGL(c2_kernel, dim3(NCODES), dim3(64), 0, stream, cbk, c2buf);
    hipLaunchKernelGGL(pprep_kernel, dim3(NCODES, NTOK), dim3(HID), 0, stream, cbk, dec_w1, Ptab);

    // ---- encoder GEMM1 + ReLU (fp32 VALU): x[16384,512] @ w1 -> hbuf ----
    hipLaunchKernelGGL((gemm_kernel<true, false>), dim3(B_ / 64, HID / 64), dim3(256), 0,
                       stream, x, enc_w1, enc_b1, hbuf, B_, HID, TD);

    // ---- encoder GEMM2 + LN (fp32 VALU): hbuf @ w2 -> zbuf ----
    hipLaunchKernelGGL((gemm_kernel<false, true>), dim3(B_ / 64, LAT / 64), dim3(256), 0,
                       stream, hbuf, enc_w2, enc_b2, zbuf, B_, LAT, HID);

    // ---- VQ (R2-proven core + P-tail): zq/idx outputs + h planes ----
    hipLaunchKernelGGL(vq_kernel3, dim3(B_ * NTOK / 64), dim3(256), 0, stream,
                       zbuf, cb_h, cb_l, cbk, c2buf, Ptab, dec_b1,
                       zq_o, idx_o, h_h, h_l);

    // ---- decoder GEMM2 (MFMA): h planes @ dw2 -> recon fp32 ----
    hipLaunchKernelGGL(gemm_split, dim3(B_ / 128, TD / 128), dim3(256), 0, stream,
                       h_h, h_l, d2t_h, d2t_l, dec_b2, recon_o, B_, TD, HID);
}